// Round 2
// baseline (522.207 us; speedup 1.0000x reference)
//
#include <hip/hip_runtime.h>
#include <hip/hip_bf16.h>
#include <stdint.h>

// B=32, L=4096, E=512(K), A=256(N).  M = B*L = 131072.
// score_kernel geometry: BM=64, BN=256(full A), BK=64, 256 thr = 4 waves,
// one wave per 64-col slice of A; B fragments loaded straight from L2-resident
// packed Wp (no LDS stage — zero intra-block reuse); A tile double-buffered in
// LDS with ONE barrier per K-step.
//
// ws layout:
//   [0,      262144)  Wp       bf16 W_enc packed [kb][chunk][n][j]
//   [262144, 294912)  dec_full f32 [32][256]
//   [294912, 819200)  scores   f32 [32][4096]
//   [819200, 827392)  m_c      f32 [2048]   per-block score max
//   [827392, 827520)  cnt      u32 [32]     per-batch completion counters
//   [1048576,5242880) o_part   f32 [2048][512] per-block weighted-feat partials

typedef __attribute__((ext_vector_type(8))) short bf16x8;
typedef __attribute__((ext_vector_type(4))) float f32x4;

__device__ __forceinline__ unsigned short f32_to_bf16(float f) {
    union { float f; unsigned u; } v; v.f = f;
    unsigned u = v.u;
    u += 0x7fffu + ((u >> 16) & 1u);   // RNE
    return (unsigned short)(u >> 16);
}

// ---------------------------------------------------------------------------
// Prep: blocks 0..31 -> dec_full[b][a] (+ block 0 zeroes cnt);
//       blocks 32..95 -> pack W_enc fp32->bf16
__global__ __launch_bounds__(256) void prep_kernel(
    const float* __restrict__ dh, const float* __restrict__ W_enc,
    const float* __restrict__ b_enc, const float* __restrict__ W_dec,
    const float* __restrict__ b_dec, unsigned short* __restrict__ Wp,
    float* __restrict__ dec_full, unsigned* __restrict__ cnt)
{
    int t = threadIdx.x;
    if (blockIdx.x < 32) {
        int b = blockIdx.x;
        if (b == 0 && t < 32) cnt[t] = 0;   // reset completion counters each launch
        __shared__ float dhs[512];
        dhs[t]       = dh[b * 512 + t];
        dhs[t + 256] = dh[b * 512 + 256 + t];
        __syncthreads();
        float a0 = 0.f, a1 = 0.f, a2 = 0.f, a3 = 0.f;
        float a4 = 0.f, a5 = 0.f, a6 = 0.f, a7 = 0.f;
        #pragma unroll 4
        for (int h = 0; h < 512; h += 8) {
            a0 += dhs[h + 0] * W_dec[(h + 0) * 256 + t];
            a1 += dhs[h + 1] * W_dec[(h + 1) * 256 + t];
            a2 += dhs[h + 2] * W_dec[(h + 2) * 256 + t];
            a3 += dhs[h + 3] * W_dec[(h + 3) * 256 + t];
            a4 += dhs[h + 4] * W_dec[(h + 4) * 256 + t];
            a5 += dhs[h + 5] * W_dec[(h + 5) * 256 + t];
            a6 += dhs[h + 6] * W_dec[(h + 6) * 256 + t];
            a7 += dhs[h + 7] * W_dec[(h + 7) * 256 + t];
        }
        dec_full[b * 256 + t] =
            ((a0 + a1) + (a2 + a3)) + ((a4 + a5) + (a6 + a7)) + b_enc[t] + b_dec[t];
    } else {
        int tid = (blockIdx.x - 32) * 256 + t;
        #pragma unroll
        for (int i = 0; i < 8; ++i) {
            int d = tid + i * 16384;               // 0..131071
            int j = d & 7;
            int n = (d >> 3) & 255;
            int chunk = (d >> 11) & 7;
            int kb = d >> 14;
            int k = kb * 64 + chunk * 8 + j;
            Wp[d] = f32_to_bf16(W_enc[k * 256 + n]);
        }
    }
}

// ---------------------------------------------------------------------------
// Fused: GEMM scores + block-local softmax partial + weighted-feat partial
//        + last-block-per-batch finalize (softmax normalize + combine).
__global__ __launch_bounds__(256, 3) void score_kernel(
    const float* __restrict__ feat, const unsigned short* __restrict__ Wp,
    const float* __restrict__ dec_full, const float* __restrict__ W_v,
    float* __restrict__ scores, float* __restrict__ m_c,
    float* __restrict__ o_part, unsigned* __restrict__ cnt,
    float* __restrict__ out)
{
    __shared__ __align__(16) unsigned short Alds[2][4096];  // 2 x 8 KB, swizzled
    __shared__ float red[4][64];
    __shared__ float sblk[64];
    __shared__ float wexp[64];
    __shared__ float mshr;
    __shared__ float red2x[128], red2y[128], red2z[128], red2w[128];
    __shared__ unsigned dflag;

    const int t = threadIdx.x;
    const int lane = t & 63;
    const int wave = t >> 6;
    const int r0 = blockIdx.x * 64;
    const int b = r0 >> 12;

    float wv[4], dec[4];
    #pragma unroll
    for (int ct = 0; ct < 4; ++ct) {
        int a = wave * 64 + ct * 16 + (lane & 15);
        wv[ct] = W_v[a];
        dec[ct] = dec_full[b * 256 + a];
    }

    f32x4 acc[4][4];
    #pragma unroll
    for (int mt = 0; mt < 4; ++mt)
        #pragma unroll
        for (int ct = 0; ct < 4; ++ct)
            acc[mt][ct] = f32x4{0.f, 0.f, 0.f, 0.f};

    // prologue: load + stage feat tile ks=0
    float4 av[4];
    #pragma unroll
    for (int it = 0; it < 4; ++it) {
        int lin = it * 256 + t;
        int m = lin >> 4, kq = lin & 15;
        av[it] = *(const float4*)(feat + (size_t)(r0 + m) * 512 + kq * 4);
    }
    #pragma unroll
    for (int it = 0; it < 4; ++it) {
        int lin = it * 256 + t;
        int m = lin >> 4, kq = lin & 15;
        ushort4 w;
        w.x = f32_to_bf16(av[it].x);
        w.y = f32_to_bf16(av[it].y);
        w.z = f32_to_bf16(av[it].z);
        w.w = f32_to_bf16(av[it].w);
        int chunk = kq >> 1, jh = kq & 1;
        *(ushort4*)(&Alds[0][m * 64 + ((chunk ^ (m & 7)) * 8) + jh * 4]) = w;
    }
    __syncthreads();

    for (int ks = 0; ks < 8; ++ks) {
        const int cur = ks & 1;
        // prefetch next feat tile (in flight across the whole compute phase)
        if (ks < 7) {
            #pragma unroll
            for (int it = 0; it < 4; ++it) {
                int lin = it * 256 + t;
                int m = lin >> 4, kq = lin & 15;
                av[it] = *(const float4*)(feat + (size_t)(r0 + m) * 512 + (ks + 1) * 64 + kq * 4);
            }
        }
        // compute: B fragments straight from global (L2-resident Wp)
        const unsigned short* Bp = Wp + ks * 16384;
        #pragma unroll
        for (int kk = 0; kk < 2; ++kk) {
            int chunk = kk * 4 + (lane >> 4);
            bf16x8 bfr[4];
            #pragma unroll
            for (int ct = 0; ct < 4; ++ct) {
                int n = wave * 64 + ct * 16 + (lane & 15);
                bfr[ct] = *(const bf16x8*)(Bp + (chunk * 256 + n) * 8);
            }
            #pragma unroll
            for (int mt = 0; mt < 4; ++mt) {
                int m = mt * 16 + (lane & 15);
                bf16x8 afr = *(const bf16x8*)(&Alds[cur][m * 64 + ((chunk ^ (m & 7)) * 8)]);
                #pragma unroll
                for (int ct = 0; ct < 4; ++ct)
                    acc[mt][ct] = __builtin_amdgcn_mfma_f32_16x16x32_bf16(
                        afr, bfr[ct], acc[mt][ct], 0, 0, 0);
            }
        }
        // stage next tile into the other buffer (no race: readers use buf cur)
        if (ks < 7) {
            #pragma unroll
            for (int it = 0; it < 4; ++it) {
                int lin = it * 256 + t;
                int m = lin >> 4, kq = lin & 15;
                ushort4 w;
                w.x = f32_to_bf16(av[it].x);
                w.y = f32_to_bf16(av[it].y);
                w.z = f32_to_bf16(av[it].z);
                w.w = f32_to_bf16(av[it].w);
                int chunk = kq >> 1, jh = kq & 1;
                *(ushort4*)(&Alds[cur ^ 1][m * 64 + ((chunk ^ (m & 7)) * 8) + jh * 4]) = w;
            }
        }
        __syncthreads();   // single barrier per K-step
    }

    // ---- score epilogue: relu(acc+dec)*wv, 16-lane butterfly, 4-wave sum
    #pragma unroll
    for (int mt = 0; mt < 4; ++mt) {
        #pragma unroll
        for (int r = 0; r < 4; ++r) {
            float p = 0.f;
            #pragma unroll
            for (int ct = 0; ct < 4; ++ct) {
                float v = acc[mt][ct][r] + dec[ct];
                v = v > 0.f ? v : 0.f;
                p += v * wv[ct];
            }
            p += __shfl_xor(p, 1);
            p += __shfl_xor(p, 2);
            p += __shfl_xor(p, 4);
            p += __shfl_xor(p, 8);
            if ((lane & 15) == 0)
                red[wave][mt * 16 + (lane >> 4) * 4 + r] = p;
        }
    }
    __syncthreads();
    if (t < 64) {
        float v = red[0][t] + red[1][t] + red[2][t] + red[3][t];
        sblk[t] = v;
        scores[r0 + t] = v;
        // block max over the 64 scores (wave 0 only)
        float m = v;
        #pragma unroll
        for (int o = 1; o < 64; o <<= 1) m = fmaxf(m, __shfl_xor(m, o));
        if (t == 0) mshr = m;
    }
    __syncthreads();
    float mb = mshr;
    if (t < 64) wexp[t] = __expf(sblk[t] - mb);
    __syncthreads();

    // ---- partial weighted-feature sum: o_c[e] = sum_l wexp[l]*feat[r0+l][e]
    // tile is L2/L3-hot (just streamed by the GEMM above)
    int e4 = t & 127, lh = t >> 7;
    float ax = 0.f, ay = 0.f, az = 0.f, aw = 0.f;
    #pragma unroll 8
    for (int i = 0; i < 32; ++i) {
        int l = i * 2 + lh;
        float wl = wexp[l];
        const float4 f = *(const float4*)(feat + (size_t)(r0 + l) * 512 + e4 * 4);
        ax += wl * f.x; ay += wl * f.y; az += wl * f.z; aw += wl * f.w;
    }
    if (lh) { red2x[e4] = ax; red2y[e4] = ay; red2z[e4] = az; red2w[e4] = aw; }
    __syncthreads();
    if (!lh) {
        float4 r;
        r.x = ax + red2x[e4]; r.y = ay + red2y[e4];
        r.z = az + red2z[e4]; r.w = aw + red2w[e4];
        *(float4*)(o_part + (size_t)blockIdx.x * 512 + e4 * 4) = r;
        if (t == 0) m_c[blockIdx.x] = mb;
    }

    // ---- signal completion; last block of this batch runs the finalize.
    __syncthreads();
    if (t == 0) {
        unsigned old = __hip_atomic_fetch_add(cnt + b, 1u,
                                              __ATOMIC_ACQ_REL,
                                              __HIP_MEMORY_SCOPE_AGENT);
        dflag = (old == 63u) ? 1u : 0u;
    }
    __syncthreads();
    if (!dflag) return;

    // ---- finalize (one block per batch): softmax over scores[b][:]
    const float* s = scores + b * 4096;
    float vals[16];
    float m = -1e30f;
    #pragma unroll
    for (int i = 0; i < 16; ++i) { vals[i] = s[t + i * 256]; m = fmaxf(m, vals[i]); }
    #pragma unroll
    for (int o = 1; o < 64; o <<= 1) m = fmaxf(m, __shfl_xor(m, o));
    if ((t & 63) == 0) red[0][t >> 6] = m;
    __syncthreads();
    m = fmaxf(fmaxf(red[0][0], red[0][1]), fmaxf(red[0][2], red[0][3]));

    float z = 0.f;
    #pragma unroll
    for (int i = 0; i < 16; ++i) { vals[i] = __expf(vals[i] - m); z += vals[i]; }
    #pragma unroll
    for (int o = 1; o < 64; o <<= 1) z += __shfl_xor(z, o);
    if ((t & 63) == 0) red[1][t >> 6] = z;
    __syncthreads();
    z = red[1][0] + red[1][1] + red[1][2] + red[1][3];
    float invz = 1.f / z;
    #pragma unroll
    for (int i = 0; i < 16; ++i)
        out[16384 + b * 4096 + t + i * 256] = vals[i] * invz;

    // ---- combine: out[b][e] = sum_c exp(m_c - M)/Z * o_part[b*64+c][e]
    if (t < 64) wexp[t] = __expf(m_c[b * 64 + t] - m) * invz;
    __syncthreads();
    float a0 = 0.f, a1 = 0.f;
    #pragma unroll 8
    for (int c = 0; c < 64; ++c) {
        const float2 v = *(const float2*)(o_part + (size_t)(b * 64 + c) * 512 + t * 2);
        a0 += wexp[c] * v.x; a1 += wexp[c] * v.y;
    }
    float2 r2; r2.x = a0; r2.y = a1;
    *(float2*)(out + b * 512 + t * 2) = r2;
}

extern "C" void kernel_launch(void* const* d_in, const int* in_sizes, int n_in,
                              void* d_out, int out_size, void* d_ws, size_t ws_size,
                              hipStream_t stream) {
    const float* feat  = (const float*)d_in[0];
    const float* dh    = (const float*)d_in[1];
    const float* W_enc = (const float*)d_in[2];
    const float* b_enc = (const float*)d_in[3];
    const float* W_dec = (const float*)d_in[4];
    const float* b_dec = (const float*)d_in[5];
    const float* W_v   = (const float*)d_in[6];
    // d_in[7] = b_v: softmax shift-invariant, unused.

    unsigned short* Wp = (unsigned short*)d_ws;
    float* dec_full = (float*)((char*)d_ws + 262144);
    float* scores   = (float*)((char*)d_ws + 294912);
    float* m_c      = (float*)((char*)d_ws + 819200);
    unsigned* cnt   = (unsigned*)((char*)d_ws + 827392);
    float* o_part   = (float*)((char*)d_ws + 1048576);
    float* out      = (float*)d_out;

    prep_kernel<<<96, 256, 0, stream>>>(dh, W_enc, b_enc, W_dec, b_dec, Wp, dec_full, cnt);
    score_kernel<<<2048, 256, 0, stream>>>(feat, Wp, dec_full, W_v, scores, m_c,
                                           o_part, cnt, out);
}

// Round 4
// 463.735 us; speedup vs baseline: 1.1261x; 1.1261x over previous
//
#include <hip/hip_runtime.h>
#include <hip/hip_bf16.h>
#include <stdint.h>

// B=32, L=4096, E=512(K), A=256(N).  M = B*L = 131072.
// score_kernel: BM=128, BN=256(full A), BK=64; 256 thr = 4 waves.
// B async-staged to LDS (Blds); A reg->cvt->LDS swizzled, feat prefetched.
// Epilogue LDS scratch aliased onto Blds (dead after K-loop).
// End-of-K-step barrier is raw s_barrier + lgkmcnt(0) only (no vmcnt drain),
// keeping feat prefetch in flight across the barrier.
// NOTE: acc = 128 AGPR/lane + ~116 VGPR => ~244 unified regs => 2 waves/SIMD
// is the honest occupancy; do NOT request 3 (forces acc spill -> timeout).
//
// ws layout:
//   [0,      262144)  Wp       bf16 W_enc packed [kb][chunk][n][j]
//   [262144, 294912)  dec_full f32 [32][256]
//   [294912, 819200)  scores   f32 [32][4096]
//   [819200, 823296)  m_c      f32 [1024]   per-block score max
//   [823296, 823424)  cnt      u32 [32]     per-batch completion counters
//   [1048576,3145728) o_part   f32 [1024][512] per-block weighted-feat partials

typedef __attribute__((ext_vector_type(8))) short bf16x8;
typedef __attribute__((ext_vector_type(4))) float f32x4;

__device__ __forceinline__ unsigned short f32_to_bf16(float f) {
    union { float f; unsigned u; } v; v.f = f;
    unsigned u = v.u;
    u += 0x7fffu + ((u >> 16) & 1u);   // RNE
    return (unsigned short)(u >> 16);
}

__device__ __forceinline__ void async_load16(const void* g, void* l) {
    __builtin_amdgcn_global_load_lds(
        (const __attribute__((address_space(1))) unsigned int*)g,
        (__attribute__((address_space(3))) unsigned int*)l, 16, 0, 0);
}

// ---------------------------------------------------------------------------
// Prep: blocks 0..31 -> dec_full[b][a] (+ block 0 zeroes cnt);
//       blocks 32..95 -> pack W_enc fp32->bf16
__global__ __launch_bounds__(256) void prep_kernel(
    const float* __restrict__ dh, const float* __restrict__ W_enc,
    const float* __restrict__ b_enc, const float* __restrict__ W_dec,
    const float* __restrict__ b_dec, unsigned short* __restrict__ Wp,
    float* __restrict__ dec_full, unsigned* __restrict__ cnt)
{
    int t = threadIdx.x;
    if (blockIdx.x < 32) {
        int b = blockIdx.x;
        if (b == 0 && t < 32) cnt[t] = 0;   // reset completion counters each launch
        __shared__ float dhs[512];
        dhs[t]       = dh[b * 512 + t];
        dhs[t + 256] = dh[b * 512 + 256 + t];
        __syncthreads();
        float a0 = 0.f, a1 = 0.f, a2 = 0.f, a3 = 0.f;
        float a4 = 0.f, a5 = 0.f, a6 = 0.f, a7 = 0.f;
        #pragma unroll 4
        for (int h = 0; h < 512; h += 8) {
            a0 += dhs[h + 0] * W_dec[(h + 0) * 256 + t];
            a1 += dhs[h + 1] * W_dec[(h + 1) * 256 + t];
            a2 += dhs[h + 2] * W_dec[(h + 2) * 256 + t];
            a3 += dhs[h + 3] * W_dec[(h + 3) * 256 + t];
            a4 += dhs[h + 4] * W_dec[(h + 4) * 256 + t];
            a5 += dhs[h + 5] * W_dec[(h + 5) * 256 + t];
            a6 += dhs[h + 6] * W_dec[(h + 6) * 256 + t];
            a7 += dhs[h + 7] * W_dec[(h + 7) * 256 + t];
        }
        dec_full[b * 256 + t] =
            ((a0 + a1) + (a2 + a3)) + ((a4 + a5) + (a6 + a7)) + b_enc[t] + b_dec[t];
    } else {
        int tid = (blockIdx.x - 32) * 256 + t;
        #pragma unroll
        for (int i = 0; i < 8; ++i) {
            int d = tid + i * 16384;               // 0..131071
            int j = d & 7;
            int n = (d >> 3) & 255;
            int chunk = (d >> 11) & 7;
            int kb = d >> 14;
            int k = kb * 64 + chunk * 8 + j;
            Wp[d] = f32_to_bf16(W_enc[k * 256 + n]);
        }
    }
}

// ---------------------------------------------------------------------------
// Fused: GEMM scores + block-local softmax partial + weighted-feat partial
//        + last-block-per-batch finalize (softmax normalize + combine).
__global__ __launch_bounds__(256, 2) void score_kernel(
    const float* __restrict__ feat, const unsigned short* __restrict__ Wp,
    const float* __restrict__ dec_full, const float* __restrict__ W_v,
    float* __restrict__ scores, float* __restrict__ m_c,
    float* __restrict__ o_part, unsigned* __restrict__ cnt,
    float* __restrict__ out)
{
    // 48 KB total: [0,16384) A tile (swizzled); [16384,49152) B tile,
    // aliased by epilogue scratch after the K-loop.
    __shared__ __align__(16) unsigned char smem[49152];
    unsigned short* const Alds = (unsigned short*)smem;
    unsigned short* const Blds = (unsigned short*)(smem + 16384);
    float* const red   = (float*)(smem + 16384);          // [4][128]
    float* const sblk  = (float*)(smem + 16384 + 2048);   // [128]
    float* const wexp  = (float*)(smem + 16384 + 2560);   // [128]
    float* const red2x = (float*)(smem + 16384 + 3072);   // [128]
    float* const red2y = (float*)(smem + 16384 + 3584);
    float* const red2z = (float*)(smem + 16384 + 4096);
    float* const red2w = (float*)(smem + 16384 + 4608);
    float* const mshr  = (float*)(smem + 16384 + 5120);
    unsigned* const dflag = (unsigned*)(smem + 16384 + 5124);

    const int t = threadIdx.x;
    const int lane = t & 63;
    const int wave = t >> 6;
    const int r0 = blockIdx.x * 128;
    const int b = r0 >> 12;

    float wv[4], dec[4];
    #pragma unroll
    for (int ct = 0; ct < 4; ++ct) {
        int a = wave * 64 + ct * 16 + (lane & 15);
        wv[ct] = W_v[a];
        dec[ct] = dec_full[b * 256 + a];
    }

    f32x4 acc[8][4];
    #pragma unroll
    for (int mt = 0; mt < 8; ++mt)
        #pragma unroll
        for (int ct = 0; ct < 4; ++ct)
            acc[mt][ct] = f32x4{0.f, 0.f, 0.f, 0.f};

    // prologue: prefetch feat tile ks=0 into registers
    float4 av[8];
    #pragma unroll
    for (int it = 0; it < 8; ++it) {
        int lin = it * 256 + t;
        int m = lin >> 4, kq = lin & 15;
        av[it] = *(const float4*)(feat + (size_t)(r0 + m) * 512 + kq * 4);
    }

    for (int ks = 0; ks < 8; ++ks) {
        // B staging: async global->LDS (L2-resident Wp)
        #pragma unroll
        for (int q = 0; q < 8; ++q) {
            int c = q * 256 + wave * 64 + lane;
            async_load16(Wp + ks * 16384 + c * 8, Blds + c * 8);
        }
        // A staging: cvt prefetched regs -> LDS (swizzled)
        #pragma unroll
        for (int it = 0; it < 8; ++it) {
            int lin = it * 256 + t;
            int m = lin >> 4, kq = lin & 15;
            ushort4 w;
            w.x = f32_to_bf16(av[it].x);
            w.y = f32_to_bf16(av[it].y);
            w.z = f32_to_bf16(av[it].z);
            w.w = f32_to_bf16(av[it].w);
            int chunk = kq >> 1, jh = kq & 1;
            *(ushort4*)(Alds + m * 64 + ((chunk ^ (m & 7)) * 8) + jh * 4) = w;
        }
        // barrier-1: __syncthreads drains vmcnt(0) == exactly the B-async wait
        __syncthreads();
        // prefetch NEXT feat tile: stays in flight across the raw barrier below
        if (ks < 7) {
            #pragma unroll
            for (int it = 0; it < 8; ++it) {
                int lin = it * 256 + t;
                int m = lin >> 4, kq = lin & 15;
                av[it] = *(const float4*)(feat + (size_t)(r0 + m) * 512 + (ks + 1) * 64 + kq * 4);
            }
        }
        // compute
        #pragma unroll
        for (int kk = 0; kk < 2; ++kk) {
            int chunk = kk * 4 + (lane >> 4);
            bf16x8 bfr[4];
            #pragma unroll
            for (int ct = 0; ct < 4; ++ct) {
                int n = wave * 64 + ct * 16 + (lane & 15);
                bfr[ct] = *(const bf16x8*)(Blds + (chunk * 256 + n) * 8);
            }
            #pragma unroll
            for (int mt = 0; mt < 8; ++mt) {
                int m = mt * 16 + (lane & 15);
                bf16x8 afr = *(const bf16x8*)(Alds + m * 64 + ((chunk ^ (m & 7)) * 8));
                #pragma unroll
                for (int ct = 0; ct < 4; ++ct)
                    acc[mt][ct] = __builtin_amdgcn_mfma_f32_16x16x32_bf16(
                        afr, bfr[ct], acc[mt][ct], 0, 0, 0);
            }
        }
        // barrier-2: LDS-only guard. Raw s_barrier + lgkmcnt(0); do NOT drain
        // vmcnt -> feat prefetch (HBM) stays in flight into next staging phase.
        __builtin_amdgcn_sched_barrier(0);
        asm volatile("s_waitcnt lgkmcnt(0)" ::: "memory");
        __builtin_amdgcn_s_barrier();
        __builtin_amdgcn_sched_barrier(0);
    }

    // ---- score epilogue: relu(acc+dec)*wv, 16-lane butterfly, 4-wave sum
    #pragma unroll
    for (int mt = 0; mt < 8; ++mt) {
        #pragma unroll
        for (int r = 0; r < 4; ++r) {
            float p = 0.f;
            #pragma unroll
            for (int ct = 0; ct < 4; ++ct) {
                float v = acc[mt][ct][r] + dec[ct];
                v = v > 0.f ? v : 0.f;
                p += v * wv[ct];
            }
            p += __shfl_xor(p, 1);
            p += __shfl_xor(p, 2);
            p += __shfl_xor(p, 4);
            p += __shfl_xor(p, 8);
            if ((lane & 15) == 0)
                red[wave * 128 + mt * 16 + (lane >> 4) * 4 + r] = p;
        }
    }
    __syncthreads();
    if (t < 128) {
        float v = red[t] + red[128 + t] + red[256 + t] + red[384 + t];
        sblk[t] = v;
        scores[r0 + t] = v;
    }
    __syncthreads();
    // block max over the 128 scores
    if (t < 64) {
        float m = fmaxf(sblk[t], sblk[t + 64]);
        #pragma unroll
        for (int o = 1; o < 64; o <<= 1) m = fmaxf(m, __shfl_xor(m, o));
        if (t == 0) *mshr = m;
    }
    __syncthreads();
    float mb = *mshr;
    if (t < 128) wexp[t] = __expf(sblk[t] - mb);
    __syncthreads();

    // ---- partial weighted-feature sum: o_c[e] = sum_l wexp[l]*feat[r0+l][e]
    // tile is L2/L3-hot (just streamed by the GEMM above)
    int e4 = t & 127, lh = t >> 7;
    float ax = 0.f, ay = 0.f, az = 0.f, aw = 0.f;
    #pragma unroll 8
    for (int i = 0; i < 64; ++i) {
        int l = i * 2 + lh;
        float wl = wexp[l];
        const float4 f = *(const float4*)(feat + (size_t)(r0 + l) * 512 + e4 * 4);
        ax += wl * f.x; ay += wl * f.y; az += wl * f.z; aw += wl * f.w;
    }
    if (lh) { red2x[e4] = ax; red2y[e4] = ay; red2z[e4] = az; red2w[e4] = aw; }
    __syncthreads();
    if (!lh) {
        float4 r;
        r.x = ax + red2x[e4]; r.y = ay + red2y[e4];
        r.z = az + red2z[e4]; r.w = aw + red2w[e4];
        *(float4*)(o_part + (size_t)blockIdx.x * 512 + e4 * 4) = r;
        if (t == 0) m_c[blockIdx.x] = mb;
    }

    // ---- signal completion; last block of this batch runs the finalize.
    __syncthreads();
    if (t == 0) {
        unsigned old = __hip_atomic_fetch_add(cnt + b, 1u,
                                              __ATOMIC_ACQ_REL,
                                              __HIP_MEMORY_SCOPE_AGENT);
        *dflag = (old == 31u) ? 1u : 0u;
    }
    __syncthreads();
    if (!*dflag) return;

    // ---- finalize (one block per batch): softmax over scores[b][:]
    const float* s = scores + b * 4096;
    float vals[16];
    float m = -1e30f;
    #pragma unroll
    for (int i = 0; i < 16; ++i) { vals[i] = s[t + i * 256]; m = fmaxf(m, vals[i]); }
    #pragma unroll
    for (int o = 1; o < 64; o <<= 1) m = fmaxf(m, __shfl_xor(m, o));
    if ((t & 63) == 0) red[t >> 6] = m;
    __syncthreads();
    m = fmaxf(fmaxf(red[0], red[1]), fmaxf(red[2], red[3]));

    float z = 0.f;
    #pragma unroll
    for (int i = 0; i < 16; ++i) { vals[i] = __expf(vals[i] - m); z += vals[i]; }
    #pragma unroll
    for (int o = 1; o < 64; o <<= 1) z += __shfl_xor(z, o);
    if ((t & 63) == 0) red[128 + (t >> 6)] = z;
    __syncthreads();
    z = red[128] + red[129] + red[130] + red[131];
    float invz = 1.f / z;
    #pragma unroll
    for (int i = 0; i < 16; ++i)
        out[16384 + b * 4096 + t + i * 256] = vals[i] * invz;

    // ---- combine: out[b][e] = sum_c exp(m_c - M)/Z * o_part[b*32+c][e]
    if (t < 32) red[256 + t] = __expf(m_c[b * 32 + t] - m) * invz;
    __syncthreads();
    float a0 = 0.f, a1 = 0.f;
    #pragma unroll 8
    for (int c = 0; c < 32; ++c) {
        const float2 v = *(const float2*)(o_part + (size_t)(b * 32 + c) * 512 + t * 2);
        a0 += red[256 + c] * v.x; a1 += red[256 + c] * v.y;
    }
    float2 r2; r2.x = a0; r2.y = a1;
    *(float2*)(out + b * 512 + t * 2) = r2;
}

extern "C" void kernel_launch(void* const* d_in, const int* in_sizes, int n_in,
                              void* d_out, int out_size, void* d_ws, size_t ws_size,
                              hipStream_t stream) {
    const float* feat  = (const float*)d_in[0];
    const float* dh    = (const float*)d_in[1];
    const float* W_enc = (const float*)d_in[2];
    const float* b_enc = (const float*)d_in[3];
    const float* W_dec = (const float*)d_in[4];
    const float* b_dec = (const float*)d_in[5];
    const float* W_v   = (const float*)d_in[6];
    // d_in[7] = b_v: softmax shift-invariant, unused.

    unsigned short* Wp = (unsigned short*)d_ws;
    float* dec_full = (float*)((char*)d_ws + 262144);
    float* scores   = (float*)((char*)d_ws + 294912);
    float* m_c      = (float*)((char*)d_ws + 819200);
    unsigned* cnt   = (unsigned*)((char*)d_ws + 823296);
    float* o_part   = (float*)((char*)d_ws + 1048576);
    float* out      = (float*)d_out;

    prep_kernel<<<96, 256, 0, stream>>>(dh, W_enc, b_enc, W_dec, b_dec, Wp, dec_full, cnt);
    score_kernel<<<1024, 256, 0, stream>>>(feat, Wp, dec_full, W_v, scores, m_c,
                                           o_part, cnt, out);
}

// Round 6
// 425.994 us; speedup vs baseline: 1.2259x; 1.0886x over previous
//
#include <hip/hip_runtime.h>
#include <hip/hip_bf16.h>
#include <stdint.h>

// B=32, L=4096, E=512(K), A=256(N).  M = B*L = 131072.
// score_kernel: BM=64, BN=256(full A), BK=64; 256 thr = 4 waves, each wave
// owns a 64-col slice of the A-dim.  B async-staged to LDS (keeps L2 latency
// off the MFMA feed — measured +60us when removed); A reg->cvt->LDS swizzled;
// feat prefetched in regs.  Plain __syncthreads barriers ONLY (raw s_barrier
// asm correlated with container hangs in r3/r5 and measured null in r4).
// acc = 64 AGPR/lane, VGPR ~72 (r2 measured) => 3 waves/SIMD; LDS 44.5KB
// => 3 blocks/CU.  Separate softmax/combine (fusion measured -16us worse).
//
// ws layout:
//   [0,      262144)  Wp       bf16 W_enc packed [kb][chunk][n][j]
//   [262144, 294912)  dec_full f32 [32][256]
//   [294912, 819200)  scores   f32 [32][4096]
//   [819200, 827392)  m_c      f32 [2048]   per-block score max
//   [827392, 827648)  MZ       f32 [64]     M[32], Z[32]
//   [1048576,5242880) o_part   f32 [2048][512] per-block weighted-feat partials

typedef __attribute__((ext_vector_type(8))) short bf16x8;
typedef __attribute__((ext_vector_type(4))) float f32x4;

__device__ __forceinline__ unsigned short f32_to_bf16(float f) {
    union { float f; unsigned u; } v; v.f = f;
    unsigned u = v.u;
    u += 0x7fffu + ((u >> 16) & 1u);   // RNE
    return (unsigned short)(u >> 16);
}

__device__ __forceinline__ void async_load16(const void* g, void* l) {
    __builtin_amdgcn_global_load_lds(
        (const __attribute__((address_space(1))) unsigned int*)g,
        (__attribute__((address_space(3))) unsigned int*)l, 16, 0, 0);
}

// ---------------------------------------------------------------------------
// Prep: blocks 0..31 -> dec_full[b][a]; blocks 32..95 -> pack W_enc fp32->bf16
__global__ __launch_bounds__(256) void prep_kernel(
    const float* __restrict__ dh, const float* __restrict__ W_enc,
    const float* __restrict__ b_enc, const float* __restrict__ W_dec,
    const float* __restrict__ b_dec, unsigned short* __restrict__ Wp,
    float* __restrict__ dec_full)
{
    int t = threadIdx.x;
    if (blockIdx.x < 32) {
        int b = blockIdx.x;
        __shared__ float dhs[512];
        dhs[t]       = dh[b * 512 + t];
        dhs[t + 256] = dh[b * 512 + 256 + t];
        __syncthreads();
        float a0 = 0.f, a1 = 0.f, a2 = 0.f, a3 = 0.f;
        float a4 = 0.f, a5 = 0.f, a6 = 0.f, a7 = 0.f;
        #pragma unroll 4
        for (int h = 0; h < 512; h += 8) {
            a0 += dhs[h + 0] * W_dec[(h + 0) * 256 + t];
            a1 += dhs[h + 1] * W_dec[(h + 1) * 256 + t];
            a2 += dhs[h + 2] * W_dec[(h + 2) * 256 + t];
            a3 += dhs[h + 3] * W_dec[(h + 3) * 256 + t];
            a4 += dhs[h + 4] * W_dec[(h + 4) * 256 + t];
            a5 += dhs[h + 5] * W_dec[(h + 5) * 256 + t];
            a6 += dhs[h + 6] * W_dec[(h + 6) * 256 + t];
            a7 += dhs[h + 7] * W_dec[(h + 7) * 256 + t];
        }
        dec_full[b * 256 + t] =
            ((a0 + a1) + (a2 + a3)) + ((a4 + a5) + (a6 + a7)) + b_enc[t] + b_dec[t];
    } else {
        int tid = (blockIdx.x - 32) * 256 + t;
        #pragma unroll
        for (int i = 0; i < 8; ++i) {
            int d = tid + i * 16384;               // 0..131071
            int j = d & 7;
            int n = (d >> 3) & 255;
            int chunk = (d >> 11) & 7;
            int kb = d >> 14;
            int k = kb * 64 + chunk * 8 + j;
            Wp[d] = f32_to_bf16(W_enc[k * 256 + n]);
        }
    }
}

// ---------------------------------------------------------------------------
// Fused: GEMM scores + block-local softmax partial + weighted-feat partial.
__global__ __launch_bounds__(256, 3) void score_kernel(
    const float* __restrict__ feat, const unsigned short* __restrict__ Wp,
    const float* __restrict__ dec_full, const float* __restrict__ W_v,
    float* __restrict__ scores, float* __restrict__ m_c,
    float* __restrict__ o_part)
{
    __shared__ __align__(16) unsigned short Alds[4096];   // 8 KB, swizzled
    __shared__ __align__(16) unsigned short Blds[16384];  // 32 KB
    __shared__ float red[4][64];
    __shared__ float sblk[64];
    __shared__ float wexp[64];
    __shared__ float mshr;
    __shared__ float red2x[128], red2y[128], red2z[128], red2w[128];

    const int t = threadIdx.x;
    const int lane = t & 63;
    const int wave = t >> 6;
    const int r0 = blockIdx.x * 64;
    const int b = r0 >> 12;

    float wv[4], dec[4];
    #pragma unroll
    for (int ct = 0; ct < 4; ++ct) {
        int a = wave * 64 + ct * 16 + (lane & 15);
        wv[ct] = W_v[a];
        dec[ct] = dec_full[b * 256 + a];
    }

    f32x4 acc[4][4];
    #pragma unroll
    for (int mt = 0; mt < 4; ++mt)
        #pragma unroll
        for (int ct = 0; ct < 4; ++ct)
            acc[mt][ct] = f32x4{0.f, 0.f, 0.f, 0.f};

    // prologue: prefetch feat tile ks=0 into registers (64 rows x 64 cols f32)
    float4 av[4];
    #pragma unroll
    for (int it = 0; it < 4; ++it) {
        int lin = it * 256 + t;
        int m = lin >> 4, kq = lin & 15;
        av[it] = *(const float4*)(feat + (size_t)(r0 + m) * 512 + kq * 4);
    }

    for (int ks = 0; ks < 8; ++ks) {
        // B staging: async global->LDS (L2/L3-resident Wp)
        #pragma unroll
        for (int q = 0; q < 8; ++q) {
            int c = q * 256 + wave * 64 + lane;
            async_load16(Wp + ks * 16384 + c * 8, Blds + c * 8);
        }
        // A staging: cvt prefetched regs -> LDS (swizzled)
        #pragma unroll
        for (int it = 0; it < 4; ++it) {
            int lin = it * 256 + t;
            int m = lin >> 4, kq = lin & 15;
            ushort4 w;
            w.x = f32_to_bf16(av[it].x);
            w.y = f32_to_bf16(av[it].y);
            w.z = f32_to_bf16(av[it].z);
            w.w = f32_to_bf16(av[it].w);
            int chunk = kq >> 1, jh = kq & 1;
            *(ushort4*)(Alds + m * 64 + ((chunk ^ (m & 7)) * 8) + jh * 4) = w;
        }
        // barrier-1: drains vmcnt(0) == the B-async wait
        __syncthreads();
        // prefetch NEXT feat tile (in flight during MFMA phase)
        if (ks < 7) {
            #pragma unroll
            for (int it = 0; it < 4; ++it) {
                int lin = it * 256 + t;
                int m = lin >> 4, kq = lin & 15;
                av[it] = *(const float4*)(feat + (size_t)(r0 + m) * 512 + (ks + 1) * 64 + kq * 4);
            }
        }
        // compute: each wave = its own 64-col slice
        #pragma unroll
        for (int kk = 0; kk < 2; ++kk) {
            int chunk = kk * 4 + (lane >> 4);
            bf16x8 bfr[4];
            #pragma unroll
            for (int ct = 0; ct < 4; ++ct) {
                int n = wave * 64 + ct * 16 + (lane & 15);
                bfr[ct] = *(const bf16x8*)(Blds + (chunk * 256 + n) * 8);
            }
            #pragma unroll
            for (int mt = 0; mt < 4; ++mt) {
                int m = mt * 16 + (lane & 15);
                bf16x8 afr = *(const bf16x8*)(Alds + m * 64 + ((chunk ^ (m & 7)) * 8));
                #pragma unroll
                for (int ct = 0; ct < 4; ++ct)
                    acc[mt][ct] = __builtin_amdgcn_mfma_f32_16x16x32_bf16(
                        afr, bfr[ct], acc[mt][ct], 0, 0, 0);
            }
        }
        // barrier-2: guard LDS reuse for next iteration
        __syncthreads();
    }

    // ---- score epilogue: relu(acc+dec)*wv, 16-lane butterfly, 4-wave sum
    #pragma unroll
    for (int mt = 0; mt < 4; ++mt) {
        #pragma unroll
        for (int r = 0; r < 4; ++r) {
            float p = 0.f;
            #pragma unroll
            for (int ct = 0; ct < 4; ++ct) {
                float v = acc[mt][ct][r] + dec[ct];
                v = v > 0.f ? v : 0.f;
                p += v * wv[ct];
            }
            p += __shfl_xor(p, 1);
            p += __shfl_xor(p, 2);
            p += __shfl_xor(p, 4);
            p += __shfl_xor(p, 8);
            if ((lane & 15) == 0)
                red[wave][mt * 16 + (lane >> 4) * 4 + r] = p;
        }
    }
    __syncthreads();
    if (t < 64) {
        float v = red[0][t] + red[1][t] + red[2][t] + red[3][t];
        sblk[t] = v;
        scores[r0 + t] = v;
        // block max over the 64 scores (wave 0 only)
        float m = v;
        #pragma unroll
        for (int o = 1; o < 64; o <<= 1) m = fmaxf(m, __shfl_xor(m, o));
        if (t == 0) mshr = m;
    }
    __syncthreads();
    float mb = mshr;
    if (t < 64) wexp[t] = __expf(sblk[t] - mb);
    __syncthreads();

    // ---- partial weighted-feature sum: o_c[e] = sum_l wexp[l]*feat[r0+l][e]
    int e4 = t & 127, lh = t >> 7;
    float ax = 0.f, ay = 0.f, az = 0.f, aw = 0.f;
    #pragma unroll 8
    for (int i = 0; i < 32; ++i) {
        int l = i * 2 + lh;
        float wl = wexp[l];
        const float4 f = *(const float4*)(feat + (size_t)(r0 + l) * 512 + e4 * 4);
        ax += wl * f.x; ay += wl * f.y; az += wl * f.z; aw += wl * f.w;
    }
    if (lh) { red2x[e4] = ax; red2y[e4] = ay; red2z[e4] = az; red2w[e4] = aw; }
    __syncthreads();
    if (!lh) {
        float4 r;
        r.x = ax + red2x[e4]; r.y = ay + red2y[e4];
        r.z = az + red2z[e4]; r.w = aw + red2w[e4];
        *(float4*)(o_part + (size_t)blockIdx.x * 512 + e4 * 4) = r;
        if (t == 0) m_c[blockIdx.x] = mb;
    }
}

// ---------------------------------------------------------------------------
// Softmax over L per batch; writes attn weights + M[b], Z[b].
__global__ __launch_bounds__(256) void softmax_kernel(
    const float* __restrict__ scores, float* __restrict__ out,
    float* __restrict__ MZ)
{
    __shared__ float sred[4];
    __shared__ float zred[4];
    int b = blockIdx.x, t = threadIdx.x;

    const float* s = scores + b * 4096;
    float vals[16];
    float m = -1e30f;
    #pragma unroll
    for (int i = 0; i < 16; ++i) { vals[i] = s[t + i * 256]; m = fmaxf(m, vals[i]); }
    #pragma unroll
    for (int o = 1; o < 64; o <<= 1) m = fmaxf(m, __shfl_xor(m, o));
    if ((t & 63) == 0) sred[t >> 6] = m;
    __syncthreads();
    m = fmaxf(fmaxf(sred[0], sred[1]), fmaxf(sred[2], sred[3]));

    float z = 0.f;
    #pragma unroll
    for (int i = 0; i < 16; ++i) { vals[i] = __expf(vals[i] - m); z += vals[i]; }
    #pragma unroll
    for (int o = 1; o < 64; o <<= 1) z += __shfl_xor(z, o);
    if ((t & 63) == 0) zred[t >> 6] = z;
    __syncthreads();
    z = zred[0] + zred[1] + zred[2] + zred[3];
    float inv = 1.f / z;
    #pragma unroll
    for (int i = 0; i < 16; ++i)
        out[16384 + b * 4096 + t + i * 256] = vals[i] * inv;
    if (t == 0) { MZ[b] = m; MZ[32 + b] = z; }
}

// ---------------------------------------------------------------------------
// Combine: out[b][e] = (1/Z_b) * sum_c exp(m_c - M_b) * o_part[b*64+c][e]
__global__ __launch_bounds__(256) void combine_kernel(
    const float* __restrict__ o_part, const float* __restrict__ m_c,
    const float* __restrict__ MZ, float* __restrict__ out)
{
    __shared__ float sc[64];
    int b = blockIdx.x, t = threadIdx.x;
    if (t < 64) sc[t] = __expf(m_c[b * 64 + t] - MZ[b]) * (1.f / MZ[32 + b]);
    __syncthreads();
    float a0 = 0.f, a1 = 0.f;
    #pragma unroll 8
    for (int c = 0; c < 64; ++c) {
        const float2 v = *(const float2*)(o_part + (size_t)(b * 64 + c) * 512 + t * 2);
        a0 += sc[c] * v.x; a1 += sc[c] * v.y;
    }
    float2 r; r.x = a0; r.y = a1;
    *(float2*)(out + b * 512 + t * 2) = r;
}

extern "C" void kernel_launch(void* const* d_in, const int* in_sizes, int n_in,
                              void* d_out, int out_size, void* d_ws, size_t ws_size,
                              hipStream_t stream) {
    const float* feat  = (const float*)d_in[0];
    const float* dh    = (const float*)d_in[1];
    const float* W_enc = (const float*)d_in[2];
    const float* b_enc = (const float*)d_in[3];
    const float* W_dec = (const float*)d_in[4];
    const float* b_dec = (const float*)d_in[5];
    const float* W_v   = (const float*)d_in[6];
    // d_in[7] = b_v: softmax shift-invariant, unused.

    unsigned short* Wp = (unsigned short*)d_ws;
    float* dec_full = (float*)((char*)d_ws + 262144);
    float* scores   = (float*)((char*)d_ws + 294912);
    float* m_c      = (float*)((char*)d_ws + 819200);
    float* MZ       = (float*)((char*)d_ws + 827392);
    float* o_part   = (float*)((char*)d_ws + 1048576);
    float* out      = (float*)d_out;

    prep_kernel<<<96, 256, 0, stream>>>(dh, W_enc, b_enc, W_dec, b_dec, Wp, dec_full);
    score_kernel<<<2048, 256, 0, stream>>>(feat, Wp, dec_full, W_v, scores, m_c, o_part);
    softmax_kernel<<<32, 256, 0, stream>>>(scores, out, MZ);
    combine_kernel<<<32, 256, 0, stream>>>(o_part, m_c, MZ, out);
}